// Round 3
// baseline (213.424 us; speedup 1.0000x reference)
//
#include <hip/hip_runtime.h>
#include <hip/hip_bf16.h>

#define NN 4096
#define FIN 128
#define FOUT 64
#define NH 8
#define KS 4          // K splits (1024 keys per block)
#define QT 32         // Q rows per block

typedef float f32x4 __attribute__((ext_vector_type(4)));
typedef _Float16 f16x8 __attribute__((ext_vector_type(8)));
typedef _Float16 h2 __attribute__((ext_vector_type(2)));
typedef unsigned long long u64;

static __device__ __forceinline__ h2 as_h2(unsigned u) { return __builtin_bit_cast(h2, u); }
static __device__ __forceinline__ unsigned as_u32(h2 v) { return __builtin_bit_cast(unsigned, v); }

// ---------------- K0: fused mask + Wc (both roles LDS-free -> no occupancy coupling).
// Blocks 0..2047: topology -> bitmask streaming. Blocks 2048..2087: Wc[128][80].
__global__ __launch_bounds__(256) void maskwc_kernel(
    const float* __restrict__ topo, u64* __restrict__ mb,
    const float* __restrict__ proj, const float* __restrict__ score_src,
    const float* __restrict__ score_dst, const float* __restrict__ skip_w,
    float* __restrict__ Wc) {
    const int tid = threadIdx.x;
    if (blockIdx.x < 2048) {               // ---- mask role
        const int w = blockIdx.x * 4 + (tid >> 6);
        const int lane = tid & 63;
        size_t base = (size_t)w * 32;
#pragma unroll 4
        for (int it = 0; it < 32; ++it) {
            size_t u = base + it;
            float t = topo[u * 64 + lane];
            u64 b = __ballot(t > -0.5e9f);
            if (lane == 0) mb[u] = b;
        }
        return;
    }
    // ---- wc role
    int idx = (blockIdx.x - 2048) * 256 + tid;
    if (idx >= FIN * 80) return;
    int i = idx / 80, c = idx % 80;
    float v = 0.f;
    if (c < 16) {
        int h = c & 7;
        const float* w = (c < 8 ? score_src : score_dst) + h * FOUT;
        const float* p = proj + (size_t)h * FIN * FOUT + (size_t)i * FOUT;
        for (int f = 0; f < FOUT; ++f) v += p[f] * w[f];
    } else {
        int f = c - 16;
        for (int h = 0; h < NH; ++h) v += skip_w[(size_t)(h * FOUT + f) * FIN + i];
        v *= 0.125f;
    }
    Wc[i * 80 + c] = v;
}

// ---------------- K1: x@Wc -> skipm (in d_out), E/F fp16 planes, Cc packed fp16, xb fp16
// C1,C2 pre-scaled by 1/8 (per-row constant, cancels exactly in the softmax ratio) so
// all fp16 products C1*E, C2*F stay far below 65504 (bound ~600 at 1.5x sigma margin).
__global__ __launch_bounds__(256) void scores_kernel(
    const float* __restrict__ x, const float* __restrict__ Wc,
    float* __restrict__ skipm, _Float16* __restrict__ Eh, _Float16* __restrict__ Fh,
    unsigned* __restrict__ Cc, _Float16* __restrict__ xb) {
    __shared__ float wcs[FIN][80];
    __shared__ float xs[16][FIN + 5];
    const int n0 = blockIdx.x * 16;
    const int tid = threadIdx.x;
    for (int i = tid; i < FIN * 80 / 4; i += 256)
        ((float4*)&wcs[0][0])[i] = ((const float4*)Wc)[i];
    const float4* xsrc = (const float4*)(x + (size_t)n0 * FIN);
    for (int i = tid; i < 16 * FIN / 4; i += 256) {
        int r = i >> 5, c4 = i & 31;
        *(float4*)&xs[r][c4 * 4] = xsrc[i];
    }
    __syncthreads();
    const int r = tid & 15;
    const int g = tid >> 4;
    float acc[4];
    float sa = 0.f;
#pragma unroll
    for (int j = 0; j < 4; ++j) acc[j] = 0.f;
#pragma unroll 4
    for (int i = 0; i < FIN; ++i) {
        float xv = xs[r][i];
        float4 p = *(float4*)&wcs[i][16 + g * 4];
        float qv = wcs[i][g];
        acc[0] += xv * p.x; acc[1] += xv * p.y; acc[2] += xv * p.z; acc[3] += xv * p.w;
        sa += xv * qv;
    }
    int n = n0 + r;
#pragma unroll
    for (int j = 0; j < 4; ++j) skipm[(size_t)n * FOUT + g * 4 + j] = acc[j];
    if (g < 8) {
        _Float16 c1 = (_Float16)(expf(sa) * 0.125f);
        _Float16 c2 = (_Float16)(expf(0.2f * sa) * 0.125f);
        unsigned short u1 = __builtin_bit_cast(unsigned short, c1);
        unsigned short u2 = __builtin_bit_cast(unsigned short, c2);
        Cc[(size_t)g * NN + n] = ((unsigned)u2 << 16) | (unsigned)u1;
    } else {
        int h = g - 8;
        Eh[(size_t)h * NN + n] = (_Float16)expf(sa);
        Fh[(size_t)h * NN + n] = (_Float16)expf(0.2f * sa);
    }
    {
        int row = tid >> 4, col0 = (tid & 15) * 8;
        const float* src = &xs[row][col0];
        f16x8 b0;
#pragma unroll
        for (int j = 0; j < 8; ++j) b0[j] = (_Float16)src[j];
        *(f16x8*)(xb + (size_t)(n0 + row) * FIN + col0) = b0;
    }
}

// ---------------- K2: Vt[h][f][n] = proj[h]^T @ x^T via fp16 MFMA
__global__ __launch_bounds__(256) void vt_kernel(
    const float* __restrict__ proj, const _Float16* __restrict__ xb,
    _Float16* __restrict__ Vt) {
    __shared__ _Float16 pT[FOUT][FIN + 8];
    const int tid = threadIdx.x;
    const int h = blockIdx.x >> 6;
    const int ng = blockIdx.x & 63;
    for (int idx = tid; idx < FIN * FOUT; idx += 256) {
        int i = idx >> 6, f = idx & 63;
        pT[f][i] = (_Float16)proj[(size_t)h * FIN * FOUT + idx];
    }
    __syncthreads();
    const int wave = tid >> 6, lane = tid & 63, q = lane >> 4, li = lane & 15;
    const int nb = ng * 64 + wave * 16;
    f32x4 acc[4];
#pragma unroll
    for (int n = 0; n < 4; ++n) acc[n] = (f32x4){0.f, 0.f, 0.f, 0.f};
#pragma unroll
    for (int kt = 0; kt < 4; ++kt) {
        f16x8 bfrag = *(const f16x8*)(xb + (size_t)(nb + li) * FIN + kt * 32 + q * 8);
#pragma unroll
        for (int ft = 0; ft < 4; ++ft) {
            f16x8 afrag = *(const f16x8*)&pT[ft * 16 + li][kt * 32 + q * 8];
            acc[ft] = __builtin_amdgcn_mfma_f32_16x16x32_f16(afrag, bfrag, acc[ft], 0, 0, 0);
        }
    }
#pragma unroll
    for (int ft = 0; ft < 4; ++ft)
#pragma unroll
        for (int reg = 0; reg < 4; ++reg)
            Vt[((size_t)h * FOUT + ft * 16 + q * 4 + reg) * NN + nb + li] = (_Float16)acc[ft][reg];
}

// ---------------- K3: attention. The old LDS-DMA path's write/read swizzles compose to
// the identity: lane (q,li) consumes exactly Vt[h][n*16+li][kb0+kt*32+q*8..+7], which is
// 16B contiguous in global. So: no LDS staging at all — direct global->register loads of
// the MFMA B-fragments, software-pipelined 2 chunks deep (2 reg sets, consume-then-reload
// through the unroll-2 body). E/F identically depth-2; masks prefetched 1 iter ahead.
// Rolling base pointers + immediate offsets keep loop address math near zero.
__attribute__((amdgpu_waves_per_eu(4)))
__global__ __launch_bounds__(256) void attn_kernel(
    const u64* __restrict__ maskbits, const _Float16* __restrict__ Vtg,
    const _Float16* __restrict__ Ehg, const _Float16* __restrict__ Fhg,
    const unsigned* __restrict__ Ccg,
    __hip_bfloat16* __restrict__ accP, float* __restrict__ rsP) {
    __shared__ u64 maskS[QT][17];         // 4.4 KB (col 16 = pad, absorbs last prefetch)
    const int tid = threadIdx.x;
    const int w = tid >> 6;
    const int lane = tid & 63, q = lane >> 4, li = lane & 15;
    const int qt = blockIdx.x >> 3, ks = (blockIdx.x >> 1) & 3, hb = blockIdx.x & 1;
    const int h = hb * 4 + w;
    const int row0 = qt * QT;
    const int kb0 = ks * 1024;

    // V fragment bases: lane (q,li) reads f-row n*16+li, keys kt*32+q*8..+7
    const _Float16* vb0 = Vtg + ((size_t)h * FOUT + li) * NN + kb0 + q * 8;
    const _Float16* vb1 = vb0 + 16 * NN;
    const _Float16* vb2 = vb0 + 32 * NN;
    const _Float16* vb3 = vb0 + 48 * NN;
    const _Float16* ehp = Ehg + (size_t)h * NN + kb0 + q * 8;
    const _Float16* fhp = Fhg + (size_t)h * NN + kb0 + q * 8;

    {   // stage 32 rows x 16 mask words (512 words, 2 per thread)
        int i0 = tid, i1 = tid + 256;
        maskS[i0 >> 4][i0 & 15] = maskbits[(size_t)(row0 + (i0 >> 4)) * 64 + ks * 16 + (i0 & 15)];
        maskS[i1 >> 4][i1 & 15] = maskbits[(size_t)(row0 + (i1 >> 4)) * 64 + ks * 16 + (i1 & 15)];
    }

    // Prologue prefetch: chunk 0 -> set A, chunk 1 -> set B (independent of the barrier)
    f16x8 vfA[4], vfB[4];
    uint4 eA, fA, eB, fB;
    vfA[0] = *(const f16x8*)(vb0);       vfA[1] = *(const f16x8*)(vb1);
    vfA[2] = *(const f16x8*)(vb2);       vfA[3] = *(const f16x8*)(vb3);
    eA = *(const uint4*)(ehp);           fA = *(const uint4*)(fhp);
    vfB[0] = *(const f16x8*)(vb0 + 32);  vfB[1] = *(const f16x8*)(vb1 + 32);
    vfB[2] = *(const f16x8*)(vb2 + 32);  vfB[3] = *(const f16x8*)(vb3 + 32);
    eB = *(const uint4*)(ehp + 32);      fB = *(const uint4*)(fhp + 32);

    __syncthreads();

    h2 c1h[2], c2h[2];
#pragma unroll
    for (int rt = 0; rt < 2; ++rt) {
        unsigned cw = Ccg[(size_t)h * NN + row0 + rt * 16 + li];
        c1h[rt] = as_h2((cw << 16) | (cw & 0xffffu));
        c2h[rt] = as_h2((cw >> 16) | (cw & 0xffff0000u));
    }
    f16x8 ones;
#pragma unroll
    for (int j = 0; j < 8; ++j) ones[j] = (_Float16)1.0f;

    f32x4 acc[2][4];
    f32x4 rsacc[2];
#pragma unroll
    for (int rt = 0; rt < 2; ++rt) {
#pragma unroll
        for (int n = 0; n < 4; ++n) acc[rt][n] = (f32x4){0.f, 0.f, 0.f, 0.f};
        rsacc[rt] = (f32x4){0.f, 0.f, 0.f, 0.f};
    }

    const u64* mp = &maskS[li][0];        // +272 u64 -> row 16+li
    u64 mw0 = mp[0], mw1 = mp[272];

// Consume set (VF,EE,FF) for this chunk, then reload the same set for chunk kt+2
// (PRE in fp16 units from the CURRENT iter base: 64 for parity 0, 96 for parity 1).
#define CHUNK_BODY(VF, EE, FF, PAR, PRE) do {                                                 \
    unsigned ew_[4] = {EE.x, EE.y, EE.z, EE.w};                                               \
    unsigned fw_[4] = {FF.x, FF.y, FF.z, FF.w};                                               \
    _Pragma("unroll")                                                                         \
    for (int rt = 0; rt < 2; ++rt) {                                                          \
        u64 mw_ = rt ? mw1 : mw0;                                                             \
        unsigned mm_ = (unsigned)(mw_ >> ((PAR) * 32 + q * 8)) & 0xffu;                       \
        unsigned mlo_ = mm_ & 0xFu, mhi_ = mm_ >> 4;                                          \
        unsigned blo_ = (mlo_ | (mlo_ << 7) | (mlo_ << 14) | (mlo_ << 21)) & 0x01010101u;     \
        unsigned bhi_ = (mhi_ | (mhi_ << 7) | (mhi_ << 14) | (mhi_ << 21)) & 0x01010101u;     \
        blo_ = (blo_ << 8) - blo_;                                                            \
        bhi_ = (bhi_ << 8) - bhi_;                                                            \
        unsigned mk_[4] = {__builtin_amdgcn_perm(0u, blo_, 0x01010000u),                      \
                           __builtin_amdgcn_perm(0u, blo_, 0x03030202u),                      \
                           __builtin_amdgcn_perm(0u, bhi_, 0x01010000u),                      \
                           __builtin_amdgcn_perm(0u, bhi_, 0x03030202u)};                     \
        union { f16x8 v; unsigned u[4]; } pf_;                                                \
        _Pragma("unroll")                                                                     \
        for (int j2 = 0; j2 < 4; ++j2) {                                                      \
            h2 t_ = c1h[rt] * as_h2(ew_[j2]);                                                 \
            h2 u_ = c2h[rt] * as_h2(fw_[j2]);                                                 \
            h2 p_ = __builtin_elementwise_max(t_, u_);                                        \
            pf_.u[j2] = as_u32(p_) & mk_[j2];                                                 \
        }                                                                                     \
        rsacc[rt] = __builtin_amdgcn_mfma_f32_16x16x32_f16(pf_.v, ones, rsacc[rt], 0, 0, 0);  \
        _Pragma("unroll")                                                                     \
        for (int n = 0; n < 4; ++n)                                                           \
            acc[rt][n] = __builtin_amdgcn_mfma_f32_16x16x32_f16(pf_.v, VF[n], acc[rt][n],     \
                                                                0, 0, 0);                     \
    }                                                                                         \
    VF[0] = *(const f16x8*)(vb0 + (PRE));                                                     \
    VF[1] = *(const f16x8*)(vb1 + (PRE));                                                     \
    VF[2] = *(const f16x8*)(vb2 + (PRE));                                                     \
    VF[3] = *(const f16x8*)(vb3 + (PRE));                                                     \
    EE = *(const uint4*)(ehp + (PRE));                                                        \
    FF = *(const uint4*)(fhp + (PRE));                                                        \
} while (0)

#pragma unroll 1
    for (int i = 0; i < 16; ++i) {
        u64 mn0 = mp[1], mn1 = mp[273];   // prefetch next iter's mask words
        CHUNK_BODY(vfA, eA, fA, 0, 64);
        CHUNK_BODY(vfB, eB, fB, 1, 96);
        mw0 = mn0; mw1 = mn1; ++mp;
        vb0 += 64; vb1 += 64; vb2 += 64; vb3 += 64;
        ehp += 64; fhp += 64;
    }
    // NOTE: the last two iterations prefetch <=128B past each plane's end; all such
    // reads land inside the contiguous workspace (next buffer), values unused.
#undef CHUNK_BODY

#pragma unroll
    for (int rt = 0; rt < 2; ++rt) {
        if (li == 0) {
#pragma unroll
            for (int reg = 0; reg < 4; ++reg)
                rsP[(size_t)(ks * NH + h) * NN + row0 + rt * 16 + q * 4 + reg] = rsacc[rt][reg];
        }
        __hip_bfloat16* ap = accP + ((size_t)(ks * NH + h) * NN + row0 + rt * 16) * 64;
#pragma unroll
        for (int n = 0; n < 4; ++n)
#pragma unroll
            for (int reg = 0; reg < 4; ++reg)
                ap[(q * 4 + reg) * 64 + n * 16 + li] = __float2bfloat16(acc[rt][n][reg]);
    }
}

// ---------------- K4: combine k-split partials + mean heads + skip + LeakyReLU
__global__ __launch_bounds__(256) void combine_kernel(
    const __hip_bfloat16* __restrict__ accP, const float* __restrict__ rsP,
    float* __restrict__ out) {
    int idx = blockIdx.x * 256 + threadIdx.x;      // 262144
    int row = idx >> 6, f = idx & 63;
    float s = 0.f;
#pragma unroll 1
    for (int h = 0; h < NH; ++h) {
        float a = 0.f, r = 0.f;
#pragma unroll
        for (int k = 0; k < KS; ++k) {
            a += __bfloat162float(accP[((size_t)(k * NH + h) * NN + row) * 64 + f]);
            r += rsP[(size_t)(k * NH + h) * NN + row];
        }
        s += a / r;
    }
    float v = s * 0.125f + out[idx];               // out currently holds skipm
    out[idx] = fmaxf(v, 0.2f * v);
}

extern "C" void kernel_launch(void* const* d_in, const int* in_sizes, int n_in,
                              void* d_out, int out_size, void* d_ws, size_t ws_size,
                              hipStream_t stream) {
    (void)in_sizes; (void)n_in; (void)out_size; (void)ws_size;
    const float* x         = (const float*)d_in[0];   // [4096,128]
    const float* topology  = (const float*)d_in[1];   // [4096,4096]
    const float* proj      = (const float*)d_in[2];   // [8,128,64]
    const float* score_src = (const float*)d_in[3];   // [8,64]
    const float* score_dst = (const float*)d_in[4];   // [8,64]
    const float* skip_w    = (const float*)d_in[5];   // [512,128]
    float* out = (float*)d_out;                       // [4096,64]

    char* ws = (char*)d_ws;
    _Float16* xb   = (_Float16*)ws;                            // 1 MB
    _Float16* Vt   = (_Float16*)(ws + 1048576);                // 4 MB
    _Float16* Eh   = (_Float16*)(ws + 5242880);                // 64 KB
    _Float16* Fh   = (_Float16*)(ws + 5308416);                // 64 KB
    unsigned* Cc   = (unsigned*)(ws + 5373952);                // 128 KB
    float* Wc      = (float*)(ws + 5505024);                   // 40 KB
    u64* maskbits  = (u64*)(ws + 5545984);                     // 2 MB
    float* rsP     = (float*)(ws + 7643136);                   // 512 KB
    __hip_bfloat16* accP = (__hip_bfloat16*)(ws + 8167424);    // 16 MB (end ~24.9 MB)
    float* skipm = out;   // skip GEMM lives in d_out; combine consumes & overwrites

    maskwc_kernel<<<2088, 256, 0, stream>>>(topology, maskbits, proj, score_src,
                                            score_dst, skip_w, Wc);
    scores_kernel<<<256, 256, 0, stream>>>(x, Wc, skipm, Eh, Fh, Cc, xb);
    vt_kernel<<<512, 256, 0, stream>>>(proj, xb, Vt);
    attn_kernel<<<1024, 256, 0, stream>>>(maskbits, Vt, Eh, Fh, Cc, accP, rsP);
    combine_kernel<<<1024, 256, 0, stream>>>(accP, rsP, out);
}

// Round 4
// 171.864 us; speedup vs baseline: 1.2418x; 1.2418x over previous
//
#include <hip/hip_runtime.h>
#include <hip/hip_bf16.h>

#define NN 4096
#define FIN 128
#define FOUT 64
#define NH 8
#define KS 4          // K splits (1024 keys per block)

typedef float f32x4 __attribute__((ext_vector_type(4)));
typedef _Float16 f16x8 __attribute__((ext_vector_type(8)));
typedef _Float16 h2 __attribute__((ext_vector_type(2)));
typedef unsigned long long u64;

static __device__ __forceinline__ h2 as_h2(unsigned u) { return __builtin_bit_cast(h2, u); }
static __device__ __forceinline__ unsigned as_u32(h2 v) { return __builtin_bit_cast(unsigned, v); }

// ---------------- K0: fused mask + Wc (both roles LDS-free -> no occupancy coupling).
// Blocks 0..2047: topology -> bitmask streaming. Blocks 2048..2087: Wc[128][80].
__global__ __launch_bounds__(256) void maskwc_kernel(
    const float* __restrict__ topo, u64* __restrict__ mb,
    const float* __restrict__ proj, const float* __restrict__ score_src,
    const float* __restrict__ score_dst, const float* __restrict__ skip_w,
    float* __restrict__ Wc) {
    const int tid = threadIdx.x;
    if (blockIdx.x < 2048) {               // ---- mask role
        const int w = blockIdx.x * 4 + (tid >> 6);
        const int lane = tid & 63;
        size_t base = (size_t)w * 32;
#pragma unroll 4
        for (int it = 0; it < 32; ++it) {
            size_t u = base + it;
            float t = topo[u * 64 + lane];
            u64 b = __ballot(t > -0.5e9f);
            if (lane == 0) mb[u] = b;
        }
        return;
    }
    // ---- wc role
    int idx = (blockIdx.x - 2048) * 256 + tid;
    if (idx >= FIN * 80) return;
    int i = idx / 80, c = idx % 80;
    float v = 0.f;
    if (c < 16) {
        int h = c & 7;
        const float* w = (c < 8 ? score_src : score_dst) + h * FOUT;
        const float* p = proj + (size_t)h * FIN * FOUT + (size_t)i * FOUT;
        for (int f = 0; f < FOUT; ++f) v += p[f] * w[f];
    } else {
        int f = c - 16;
        for (int h = 0; h < NH; ++h) v += skip_w[(size_t)(h * FOUT + f) * FIN + i];
        v *= 0.125f;
    }
    Wc[i * 80 + c] = v;
}

// ---------------- K1: x@Wc -> skipm (in d_out), E/F fp16 planes, Cc packed fp16, xb fp16
// C1,C2 pre-scaled by 1/8 (per-row constant, cancels exactly in the softmax ratio) so
// all fp16 products C1*E, C2*F stay far below 65504 (bound ~600 at 1.5x sigma margin).
__global__ __launch_bounds__(256) void scores_kernel(
    const float* __restrict__ x, const float* __restrict__ Wc,
    float* __restrict__ skipm, _Float16* __restrict__ Eh, _Float16* __restrict__ Fh,
    unsigned* __restrict__ Cc, _Float16* __restrict__ xb) {
    __shared__ float wcs[FIN][80];
    __shared__ float xs[16][FIN + 5];
    const int n0 = blockIdx.x * 16;
    const int tid = threadIdx.x;
    for (int i = tid; i < FIN * 80 / 4; i += 256)
        ((float4*)&wcs[0][0])[i] = ((const float4*)Wc)[i];
    const float4* xsrc = (const float4*)(x + (size_t)n0 * FIN);
    for (int i = tid; i < 16 * FIN / 4; i += 256) {
        int r = i >> 5, c4 = i & 31;
        *(float4*)&xs[r][c4 * 4] = xsrc[i];
    }
    __syncthreads();
    const int r = tid & 15;
    const int g = tid >> 4;
    float acc[4];
    float sa = 0.f;
#pragma unroll
    for (int j = 0; j < 4; ++j) acc[j] = 0.f;
#pragma unroll 4
    for (int i = 0; i < FIN; ++i) {
        float xv = xs[r][i];
        float4 p = *(float4*)&wcs[i][16 + g * 4];
        float qv = wcs[i][g];
        acc[0] += xv * p.x; acc[1] += xv * p.y; acc[2] += xv * p.z; acc[3] += xv * p.w;
        sa += xv * qv;
    }
    int n = n0 + r;
#pragma unroll
    for (int j = 0; j < 4; ++j) skipm[(size_t)n * FOUT + g * 4 + j] = acc[j];
    if (g < 8) {
        _Float16 c1 = (_Float16)(expf(sa) * 0.125f);
        _Float16 c2 = (_Float16)(expf(0.2f * sa) * 0.125f);
        unsigned short u1 = __builtin_bit_cast(unsigned short, c1);
        unsigned short u2 = __builtin_bit_cast(unsigned short, c2);
        Cc[(size_t)g * NN + n] = ((unsigned)u2 << 16) | (unsigned)u1;
    } else {
        int h = g - 8;
        Eh[(size_t)h * NN + n] = (_Float16)expf(sa);
        Fh[(size_t)h * NN + n] = (_Float16)expf(0.2f * sa);
    }
    {
        int row = tid >> 4, col0 = (tid & 15) * 8;
        const float* src = &xs[row][col0];
        f16x8 b0;
#pragma unroll
        for (int j = 0; j < 8; ++j) b0[j] = (_Float16)src[j];
        *(f16x8*)(xb + (size_t)(n0 + row) * FIN + col0) = b0;
    }
}

// ---------------- K2: Vt[h][f][n] = proj[h]^T @ x^T via fp16 MFMA
__global__ __launch_bounds__(256) void vt_kernel(
    const float* __restrict__ proj, const _Float16* __restrict__ xb,
    _Float16* __restrict__ Vt) {
    __shared__ _Float16 pT[FOUT][FIN + 8];
    const int tid = threadIdx.x;
    const int h = blockIdx.x >> 6;
    const int ng = blockIdx.x & 63;
    for (int idx = tid; idx < FIN * FOUT; idx += 256) {
        int i = idx >> 6, f = idx & 63;
        pT[f][i] = (_Float16)proj[(size_t)h * FIN * FOUT + idx];
    }
    __syncthreads();
    const int wave = tid >> 6, lane = tid & 63, q = lane >> 4, li = lane & 15;
    const int nb = ng * 64 + wave * 16;
    f32x4 acc[4];
#pragma unroll
    for (int n = 0; n < 4; ++n) acc[n] = (f32x4){0.f, 0.f, 0.f, 0.f};
#pragma unroll
    for (int kt = 0; kt < 4; ++kt) {
        f16x8 bfrag = *(const f16x8*)(xb + (size_t)(nb + li) * FIN + kt * 32 + q * 8);
#pragma unroll
        for (int ft = 0; ft < 4; ++ft) {
            f16x8 afrag = *(const f16x8*)&pT[ft * 16 + li][kt * 32 + q * 8];
            acc[ft] = __builtin_amdgcn_mfma_f32_16x16x32_f16(afrag, bfrag, acc[ft], 0, 0, 0);
        }
    }
#pragma unroll
    for (int ft = 0; ft < 4; ++ft)
#pragma unroll
        for (int reg = 0; reg < 4; ++reg)
            Vt[((size_t)h * FOUT + ft * 16 + q * 4 + reg) * NN + nb + li] = (_Float16)acc[ft][reg];
}

// ---------------- K3: attention, SHARED-head blocks.
// Block = 1 head x 128 Q-rows (4 waves x 32 rows; per-wave compute identical to the
// proven R1 structure). The 4KB V-chunk is staged ONCE per block into a shared LDS
// quad-buffer: each wave DMAs its own 1KB quarter (wave w supplies f-rows w*16..+15,
// same identity-composed swizzle with c=w), then a raw s_barrier publishes it.
// Quad-buffer + depth-2 prefetch: the per-body s_waitcnt vmcnt(4) leaves
// {DMA(k+1), EF(k+1), DMA(k+2)} in flight, draining only ops issued >=1-2 full bodies
// earlier. V L2-traffic drops 4x (512MB -> 128MB/dispatch); grid mapping pins each
// (ks,h) V-slice to one XCD (XCD = bid&7 = h; working set 512KB << 4MB L2).
// All 32 bodies identical; tail over-prefetches land inside the contiguous workspace
// and target buffers that are never read again.
__attribute__((amdgpu_waves_per_eu(4)))
__global__ __launch_bounds__(256) void attn_kernel(
    const u64* __restrict__ maskbits, const _Float16* __restrict__ Vtg,
    const _Float16* __restrict__ Ehg, const _Float16* __restrict__ Fhg,
    const unsigned* __restrict__ Ccg,
    __hip_bfloat16* __restrict__ accP, float* __restrict__ rsP) {
    __shared__ u64 maskS[4][32][18];      // 18.4 KB (word 16+ = pad, absorbs prefetch)
    __shared__ char vbuf[4][4096];        // 16 KB shared quad-buffer
    const int tid = threadIdx.x;
    const int w = tid >> 6;
    const int lane = tid & 63, q = lane >> 4, li = lane & 15;
    const int qt = blockIdx.x >> 5;       // 0..31
    const int ks = (blockIdx.x >> 3) & 3;
    const int h  = blockIdx.x & 7;        // XCD = h -> per-XCD V working set 512KB
    const int row0 = qt * 128 + w * 32;   // this wave's 32 Q-rows
    const int kb0 = ks * 1024;

    const int r_ = lane >> 2;
    const int sg = ((lane & 3) - (r_ >> 1)) & 3;
    // wave w supplies f-rows w*16 + r_ of the shared tile (identity-composed swizzle)
    const _Float16* gsrc = Vtg + ((size_t)h * FOUT + w * 16 + r_) * NN + kb0 + sg * 8;
    const int rdoff = li * 64 + ((q + (li >> 1)) & 3) * 16;     // bytes within 4KB buf
    const _Float16* ehp = Ehg + (size_t)h * NN + kb0 + q * 8;
    const _Float16* fhp = Fhg + (size_t)h * NN + kb0 + q * 8;

#define DMA_TILE(B, OFF) \
    __builtin_amdgcn_global_load_lds( \
        (const __attribute__((address_space(1))) void*)(gsrc + (OFF)), \
        (__attribute__((address_space(3))) void*)&vbuf[B][w * 1024], 16, 0, 0)

    {   // stage this wave's 32 rows x 16 mask words (512 words, 8 per lane)
#pragma unroll
        for (int j = 0; j < 8; ++j) {
            int t = lane + j * 64;
            maskS[w][t >> 4][t & 15] =
                maskbits[(size_t)(row0 + (t >> 4)) * 64 + ks * 16 + (t & 15)];
        }
    }
    // Prologue: EF(0) -> set 0; DMA chunks 0,1 into buffers 0,1.
    uint4 e0 = *(const uint4*)(ehp);
    uint4 f0 = *(const uint4*)(fhp);
    uint4 e1, f1;
    DMA_TILE(0, 0);
    DMA_TILE(1, 32);

    h2 c1h[2], c2h[2];
#pragma unroll
    for (int rt = 0; rt < 2; ++rt) {
        unsigned cw = Ccg[(size_t)h * NN + row0 + rt * 16 + li];
        c1h[rt] = as_h2((cw << 16) | (cw & 0xffffu));
        c2h[rt] = as_h2((cw >> 16) | (cw & 0xffff0000u));
    }
    __syncthreads();                      // drains all prologue VMEM; masks visible

    f16x8 ones;
#pragma unroll
    for (int j = 0; j < 8; ++j) ones[j] = (_Float16)1.0f;

    f32x4 acc[2][4];
    f32x4 rsacc[2];
#pragma unroll
    for (int rt = 0; rt < 2; ++rt) {
#pragma unroll
        for (int n = 0; n < 4; ++n) acc[rt][n] = (f32x4){0.f, 0.f, 0.f, 0.f};
        rsacc[rt] = (f32x4){0.f, 0.f, 0.f, 0.f};
    }

    const u64* mp0 = &maskS[w][li][0];
    const u64* mp1 = &maskS[w][16 + li][0];
    u64 ma0 = mp0[0], ma1 = mp1[0];       // mask words, chunk-pair 0
    u64 mb0 = mp0[1], mb1 = mp1[1];       // chunk-pair 1

// Body for kt = 4i + K2. Issue order: EF(kt+1) loads, then DMA(kt+2); the
// s_waitcnt vmcnt(4) drains exactly {DMA(kt), EF(kt)} (issued 1-2 bodies ago),
// leaving {DMA(kt+1), EF(kt+1), DMA(kt+2)} in flight. Raw s_barrier publishes
// buffer kt%4 (each wave has awaited its own DMA quarter).
#define BODY(K2, EU, FU, EN, FN, MW0, MW1) do {                                               \
    EN = *(const uint4*)(ehp + ((K2) + 1) * 32);                                              \
    FN = *(const uint4*)(fhp + ((K2) + 1) * 32);                                              \
    asm volatile("" ::: "memory");             /* pin EF prefetch before the DMA */           \
    DMA_TILE(((K2) + 2) & 3, ((K2) + 2) * 32);                                                \
    asm volatile("s_waitcnt vmcnt(4)" ::: "memory");                                          \
    __builtin_amdgcn_s_barrier();                                                             \
    f16x8 vf_[4];                                                                             \
    _Pragma("unroll")                                                                         \
    for (int n = 0; n < 4; ++n)                                                               \
        vf_[n] = *(const f16x8*)&vbuf[K2][n * 1024 + rdoff];                                  \
    unsigned ew_[4] = {EU.x, EU.y, EU.z, EU.w};                                               \
    unsigned fw_[4] = {FU.x, FU.y, FU.z, FU.w};                                               \
    _Pragma("unroll")                                                                         \
    for (int rt = 0; rt < 2; ++rt) {                                                          \
        u64 mw_ = rt ? (MW1) : (MW0);                                                         \
        unsigned mm_ = (unsigned)(mw_ >> (((K2) & 1) * 32 + q * 8)) & 0xffu;                  \
        unsigned mlo_ = mm_ & 0xFu, mhi_ = mm_ >> 4;                                          \
        unsigned blo_ = (mlo_ | (mlo_ << 7) | (mlo_ << 14) | (mlo_ << 21)) & 0x01010101u;     \
        unsigned bhi_ = (mhi_ | (mhi_ << 7) | (mhi_ << 14) | (mhi_ << 21)) & 0x01010101u;     \
        blo_ = (blo_ << 8) - blo_;                                                            \
        bhi_ = (bhi_ << 8) - bhi_;                                                            \
        unsigned mk_[4] = {__builtin_amdgcn_perm(0u, blo_, 0x01010000u),                      \
                           __builtin_amdgcn_perm(0u, blo_, 0x03030202u),                      \
                           __builtin_amdgcn_perm(0u, bhi_, 0x01010000u),                      \
                           __builtin_amdgcn_perm(0u, bhi_, 0x03030202u)};                     \
        union { f16x8 v; unsigned u[4]; } pf_;                                                \
        _Pragma("unroll")                                                                     \
        for (int j2 = 0; j2 < 4; ++j2) {                                                      \
            h2 t_ = c1h[rt] * as_h2(ew_[j2]);                                                 \
            h2 u_ = c2h[rt] * as_h2(fw_[j2]);                                                 \
            h2 p_ = __builtin_elementwise_max(t_, u_);                                        \
            pf_.u[j2] = as_u32(p_) & mk_[j2];                                                 \
        }                                                                                     \
        rsacc[rt] = __builtin_amdgcn_mfma_f32_16x16x32_f16(pf_.v, ones, rsacc[rt], 0, 0, 0);  \
        _Pragma("unroll")                                                                     \
        for (int n = 0; n < 4; ++n)                                                           \
            acc[rt][n] = __builtin_amdgcn_mfma_f32_16x16x32_f16(pf_.v, vf_[n], acc[rt][n],    \
                                                                0, 0, 0);                     \
    }                                                                                         \
} while (0)

#pragma unroll 1
    for (int i = 0; i < 8; ++i) {         // 4 chunks (128 keys) per iteration
        u64 na0 = mp0[2], na1 = mp1[2];   // prefetch next two chunk-pairs' mask words
        u64 nb0 = mp0[3], nb1 = mp1[3];
        BODY(0, e0, f0, e1, f1, ma0, ma1);
        BODY(1, e1, f1, e0, f0, ma0, ma1);
        BODY(2, e0, f0, e1, f1, mb0, mb1);
        BODY(3, e1, f1, e0, f0, mb0, mb1);
        ma0 = na0; ma1 = na1; mb0 = nb0; mb1 = nb1;
        mp0 += 2; mp1 += 2;
        gsrc += 128; ehp += 128; fhp += 128;
    }
#undef BODY
#undef DMA_TILE

    asm volatile("s_waitcnt vmcnt(0)" ::: "memory");   // drain tail over-prefetches

#pragma unroll
    for (int rt = 0; rt < 2; ++rt) {
        if (li == 0) {
#pragma unroll
            for (int reg = 0; reg < 4; ++reg)
                rsP[(size_t)(ks * NH + h) * NN + row0 + rt * 16 + q * 4 + reg] = rsacc[rt][reg];
        }
        __hip_bfloat16* ap = accP + ((size_t)(ks * NH + h) * NN + row0 + rt * 16) * 64;
#pragma unroll
        for (int n = 0; n < 4; ++n)
#pragma unroll
            for (int reg = 0; reg < 4; ++reg)
                ap[(q * 4 + reg) * 64 + n * 16 + li] = __float2bfloat16(acc[rt][n][reg]);
    }
}

// ---------------- K4: combine k-split partials + mean heads + skip + LeakyReLU
__global__ __launch_bounds__(256) void combine_kernel(
    const __hip_bfloat16* __restrict__ accP, const float* __restrict__ rsP,
    float* __restrict__ out) {
    int idx = blockIdx.x * 256 + threadIdx.x;      // 262144
    int row = idx >> 6, f = idx & 63;
    float s = 0.f;
#pragma unroll 1
    for (int h = 0; h < NH; ++h) {
        float a = 0.f, r = 0.f;
#pragma unroll
        for (int k = 0; k < KS; ++k) {
            a += __bfloat162float(accP[((size_t)(k * NH + h) * NN + row) * 64 + f]);
            r += rsP[(size_t)(k * NH + h) * NN + row];
        }
        s += a / r;
    }
    float v = s * 0.125f + out[idx];               // out currently holds skipm
    out[idx] = fmaxf(v, 0.2f * v);
}

extern "C" void kernel_launch(void* const* d_in, const int* in_sizes, int n_in,
                              void* d_out, int out_size, void* d_ws, size_t ws_size,
                              hipStream_t stream) {
    (void)in_sizes; (void)n_in; (void)out_size; (void)ws_size;
    const float* x         = (const float*)d_in[0];   // [4096,128]
    const float* topology  = (const float*)d_in[1];   // [4096,4096]
    const float* proj      = (const float*)d_in[2];   // [8,128,64]
    const float* score_src = (const float*)d_in[3];   // [8,64]
    const float* score_dst = (const float*)d_in[4];   // [8,64]
    const float* skip_w    = (const float*)d_in[5];   // [512,128]
    float* out = (float*)d_out;                       // [4096,64]

    char* ws = (char*)d_ws;
    _Float16* xb   = (_Float16*)ws;                            // 1 MB
    _Float16* Vt   = (_Float16*)(ws + 1048576);                // 4 MB
    _Float16* Eh   = (_Float16*)(ws + 5242880);                // 64 KB
    _Float16* Fh   = (_Float16*)(ws + 5308416);                // 64 KB
    unsigned* Cc   = (unsigned*)(ws + 5373952);                // 128 KB
    float* Wc      = (float*)(ws + 5505024);                   // 40 KB
    u64* maskbits  = (u64*)(ws + 5545984);                     // 2 MB
    float* rsP     = (float*)(ws + 7643136);                   // 512 KB
    __hip_bfloat16* accP = (__hip_bfloat16*)(ws + 8167424);    // 16 MB (end ~24.9 MB)
    float* skipm = out;   // skip GEMM lives in d_out; combine consumes & overwrites

    maskwc_kernel<<<2088, 256, 0, stream>>>(topology, maskbits, proj, score_src,
                                            score_dst, skip_w, Wc);
    scores_kernel<<<256, 256, 0, stream>>>(x, Wc, skipm, Eh, Fh, Cc, xb);
    vt_kernel<<<512, 256, 0, stream>>>(proj, xb, Vt);
    attn_kernel<<<1024, 256, 0, stream>>>(maskbits, Vt, Eh, Fh, Cc, accP, rsP);
    combine_kernel<<<1024, 256, 0, stream>>>(accP, rsP, out);
}